// Round 5
// baseline (101.354 us; speedup 1.0000x reference)
//
#include <hip/hip_runtime.h>

#define NV  778
#define NT  256
#define VPT 4          // ceil(778/256)

__global__ __launch_bounds__(NT, 4)   // cap at 128 VGPR (occupancy cliff)
void newloss_gather(const float* __restrict__ vertices,
                    const float* __restrict__ phi_right,
                    const float* __restrict__ phi_left,
                    float* __restrict__ out)
{
    const int b    = blockIdx.x;
    const int tid  = threadIdx.x;
    const int lane = tid & 63;
    const int wave = tid >> 6;

    __shared__ float red[4][12];
    __shared__ float rsum[4];

    const float* vb = vertices + (size_t)b * (2 * NV * 3);

    // ---- load this thread's vertices (both hands) into registers, track bbox ----
    float vx[2][VPT], vy[2][VPT], vz[2][VPT];
    float mn[6], mx[6];
#pragma unroll
    for (int i = 0; i < 6; ++i) { mn[i] = 3.0e38f; mx[i] = -3.0e38f; }

#pragma unroll
    for (int h = 0; h < 2; ++h) {
        const float* vh = vb + h * (NV * 3);
#pragma unroll
        for (int k = 0; k < VPT; ++k) {
            int v = tid + k * NT;
            float a = 0.f, c = 0.f, d = 0.f;
            if (v < NV) {
                a = vh[v * 3 + 0];
                c = vh[v * 3 + 1];
                d = vh[v * 3 + 2];
                mn[h * 3 + 0] = fminf(mn[h * 3 + 0], a);
                mx[h * 3 + 0] = fmaxf(mx[h * 3 + 0], a);
                mn[h * 3 + 1] = fminf(mn[h * 3 + 1], c);
                mx[h * 3 + 1] = fmaxf(mx[h * 3 + 1], c);
                mn[h * 3 + 2] = fminf(mn[h * 3 + 2], d);
                mx[h * 3 + 2] = fmaxf(mx[h * 3 + 2], d);
            }
            vx[h][k] = a; vy[h][k] = c; vz[h][k] = d;
        }
    }

    // ---- bbox reduce: wave shuffle, then cross-wave via LDS ----
#pragma unroll
    for (int off = 32; off > 0; off >>= 1) {
#pragma unroll
        for (int i = 0; i < 6; ++i) {
            mn[i] = fminf(mn[i], __shfl_xor(mn[i], off, 64));
            mx[i] = fmaxf(mx[i], __shfl_xor(mx[i], off, 64));
        }
    }
    if (lane == 0) {
#pragma unroll
        for (int i = 0; i < 6; ++i) { red[wave][i] = mn[i]; red[wave][6 + i] = mx[i]; }
    }
    __syncthreads();

    float cen[6], isc[2];
    {
        float fmn[6], fmx[6];
#pragma unroll
        for (int i = 0; i < 6; ++i) {
            fmn[i] = fminf(fminf(red[0][i], red[1][i]), fminf(red[2][i], red[3][i]));
            fmx[i] = fmaxf(fmaxf(red[0][6 + i], red[1][6 + i]),
                           fmaxf(red[2][6 + i], red[3][6 + i]));
            cen[i] = 0.5f * (fmn[i] + fmx[i]);
        }
#pragma unroll
        for (int h = 0; h < 2; ++h) {
            float ext = fmaxf(fmx[h * 3 + 0] - fmn[h * 3 + 0],
                        fmaxf(fmx[h * 3 + 1] - fmn[h * 3 + 1],
                              fmx[h * 3 + 2] - fmn[h * 3 + 2]));
            isc[h] = 1.0f / (0.55f * ext);   // (1+0.1)*0.5
        }
    }

    // ---- pre-transform vertices to grid coords IN REGISTERS ----
    // vert hand h is only ever sampled with bbox of hand (1-h):
    //   s=0: verts[hand1] w/ bbox0 -> phi_right ; s=1: verts[hand0] w/ bbox1 -> phi_left
#pragma unroll
    for (int h = 0; h < 2; ++h) {
        const int hb = 1 - h;
        const float cx = cen[hb * 3 + 0], cy = cen[hb * 3 + 1], cz = cen[hb * 3 + 2];
        const float is = isc[hb];
#pragma unroll
        for (int k = 0; k < VPT; ++k) {
            vx[h][k] = fmaf((vx[h][k] - cx) * is, 15.5f, 15.5f);
            vy[h][k] = fmaf((vy[h][k] - cy) * is, 15.5f, 15.5f);
            vz[h][k] = fmaf((vz[h][k] - cz) * is, 15.5f, 15.5f);
        }
    }

    const float* volR = phi_right + (size_t)b * 32768;   // sampled by hand-1 verts
    const float* volL = phi_left  + (size_t)b * 32768;   // sampled by hand-0 verts

    // ---- gather: quad-merged x-taps (4 float4 + rare masked dword per vert-vol) ----
    float acc = 0.0f;
#pragma unroll
    for (int k = 0; k < VPT; ++k) {
        int v = tid + k * NT;
        if (v >= NV) continue;
#pragma unroll
        for (int h = 0; h < 2; ++h) {
            const float* vol = (h == 1) ? volR : volL;
            float ix = vx[h][k], iy = vy[h][k], iz = vz[h][k];

            float x0f = fminf(fmaxf(floorf(ix), 0.0f), 31.0f);
            float y0f = fminf(fmaxf(floorf(iy), 0.0f), 31.0f);
            float z0f = fminf(fmaxf(floorf(iz), 0.0f), 31.0f);
            float fx = ix - x0f, fy = iy - y0f, fz = iz - z0f;  // unclamped (ref)
            int x0 = (int)x0f, y0 = (int)y0f, z0 = (int)z0f;
            int y1 = min(y0 + 1, 31), z1 = min(z0 + 1, 31);

            const int p  = x0 & 3;          // position within 16B quad
            const int xb = x0 & ~3;         // quad-aligned x base

            int o00 = z0 * 1024 + y0 * 32 + xb;
            int o01 = z0 * 1024 + y1 * 32 + xb;
            int o10 = z1 * 1024 + y0 * 32 + xb;
            int o11 = z1 * 1024 + y1 * 32 + xb;

            float4 q00 = *(const float4*)(vol + o00);
            float4 q01 = *(const float4*)(vol + o01);
            float4 q10 = *(const float4*)(vol + o10);
            float4 q11 = *(const float4*)(vol + o11);

            // x1 value when it falls outside the quad (p==3 && x0<31): one
            // masked dword at quad_base+4. When x0==31 (x1==x0), q.w is correct.
            float e00 = q00.w, e01 = q01.w, e10 = q10.w, e11 = q11.w;
            if ((p == 3) && (x0 < 31)) {
                e00 = vol[o00 + 4];
                e01 = vol[o01 + 4];
                e10 = vol[o10 + 4];
                e11 = vol[o11 + 4];
            }

            const bool p1 = (p & 1) != 0;
            const bool p2 = (p & 2) != 0;

            // v0 = quad[p], v1 = quad[p+1] (or ext) — static selects, no scratch
            float a00 = p1 ? (p2 ? q00.w : q00.y) : (p2 ? q00.z : q00.x);
            float b00 = p1 ? (p2 ? e00   : q00.z) : (p2 ? q00.w : q00.y);
            float a01 = p1 ? (p2 ? q01.w : q01.y) : (p2 ? q01.z : q01.x);
            float b01 = p1 ? (p2 ? e01   : q01.z) : (p2 ? q01.w : q01.y);
            float a10 = p1 ? (p2 ? q10.w : q10.y) : (p2 ? q10.z : q10.x);
            float b10 = p1 ? (p2 ? e10   : q10.z) : (p2 ? q10.w : q10.y);
            float a11 = p1 ? (p2 ? q11.w : q11.y) : (p2 ? q11.z : q11.x);
            float b11 = p1 ? (p2 ? e11   : q11.z) : (p2 ? q11.w : q11.y);

            float c00 = a00 + fx * (b00 - a00);
            float c01 = a01 + fx * (b01 - a01);
            float c10 = a10 + fx * (b10 - a10);
            float c11 = a11 + fx * (b11 - a11);
            float c0  = c00 + fy * (c01 - c00);
            float c1  = c10 + fy * (c11 - c10);
            acc += c0 + fz * (c1 - c0);
        }
    }

    // ---- reduce & write ----
    acc *= 0.25f;   // / num_hand^2
#pragma unroll
    for (int off = 32; off > 0; off >>= 1) acc += __shfl_xor(acc, off, 64);
    if (lane == 0) rsum[wave] = acc;
    __syncthreads();
    if (tid == 0) out[b] = rsum[0] + rsum[1] + rsum[2] + rsum[3];
}

extern "C" void kernel_launch(void* const* d_in, const int* in_sizes, int n_in,
                              void* d_out, int out_size, void* d_ws, size_t ws_size,
                              hipStream_t stream) {
    const float* vertices  = (const float*)d_in[0];
    const float* phi_right = (const float*)d_in[1];
    const float* phi_left  = (const float*)d_in[2];
    float* out = (float*)d_out;

    newloss_gather<<<dim3((unsigned)out_size), dim3(NT), 0, stream>>>(
        vertices, phi_right, phi_left, out);
}

// Round 6
// 54.495 us; speedup vs baseline: 1.8599x; 1.8599x over previous
//
#include <hip/hip_runtime.h>

#define NV     778
#define NT     256
#define VPT    4              // ceil(778/256)
#define NITEMS (2 * NV)       // 1556 (vert, hand) samples per batch

__global__ __launch_bounds__(NT, 4)   // cap at 128 VGPR
void newloss_sorted(const float* __restrict__ vertices,
                    const float* __restrict__ phi_right,
                    const float* __restrict__ phi_left,
                    float* __restrict__ out)
{
    const int b    = blockIdx.x;
    const int tid  = threadIdx.x;
    const int lane = tid & 63;
    const int wave = tid >> 6;

    __shared__ float4 sorted[NITEMS];   // z-sorted (ix,iy,iz, volbit)
    __shared__ int    hist[32];
    __shared__ int    cursor[32];
    __shared__ float  red[4][12];
    __shared__ float  rsum[4];

    const float* vb = vertices + (size_t)b * (2 * NV * 3);

    // ---- load this thread's vertices (both hands) into registers, track bbox ----
    float vx[2][VPT], vy[2][VPT], vz[2][VPT];
    float mn[6], mx[6];
#pragma unroll
    for (int i = 0; i < 6; ++i) { mn[i] = 3.0e38f; mx[i] = -3.0e38f; }

#pragma unroll
    for (int h = 0; h < 2; ++h) {
        const float* vh = vb + h * (NV * 3);
#pragma unroll
        for (int k = 0; k < VPT; ++k) {
            int v = tid + k * NT;
            float a = 0.f, c = 0.f, d = 0.f;
            if (v < NV) {
                a = vh[v * 3 + 0];
                c = vh[v * 3 + 1];
                d = vh[v * 3 + 2];
                mn[h * 3 + 0] = fminf(mn[h * 3 + 0], a);
                mx[h * 3 + 0] = fmaxf(mx[h * 3 + 0], a);
                mn[h * 3 + 1] = fminf(mn[h * 3 + 1], c);
                mx[h * 3 + 1] = fmaxf(mx[h * 3 + 1], c);
                mn[h * 3 + 2] = fminf(mn[h * 3 + 2], d);
                mx[h * 3 + 2] = fmaxf(mx[h * 3 + 2], d);
            }
            vx[h][k] = a; vy[h][k] = c; vz[h][k] = d;
        }
    }

    // ---- bbox reduce: wave shuffle, then cross-wave via LDS ----
#pragma unroll
    for (int off = 32; off > 0; off >>= 1) {
#pragma unroll
        for (int i = 0; i < 6; ++i) {
            mn[i] = fminf(mn[i], __shfl_xor(mn[i], off, 64));
            mx[i] = fmaxf(mx[i], __shfl_xor(mx[i], off, 64));
        }
    }
    if (lane == 0) {
#pragma unroll
        for (int i = 0; i < 6; ++i) { red[wave][i] = mn[i]; red[wave][6 + i] = mx[i]; }
    }
    if (tid < 32) hist[tid] = 0;
    __syncthreads();

    float cen[6], isc[2];
    {
        float fmn[6], fmx[6];
#pragma unroll
        for (int i = 0; i < 6; ++i) {
            fmn[i] = fminf(fminf(red[0][i], red[1][i]), fminf(red[2][i], red[3][i]));
            fmx[i] = fmaxf(fmaxf(red[0][6 + i], red[1][6 + i]),
                           fmaxf(red[2][6 + i], red[3][6 + i]));
            cen[i] = 0.5f * (fmn[i] + fmx[i]);
        }
#pragma unroll
        for (int h = 0; h < 2; ++h) {
            float ext = fmaxf(fmx[h * 3 + 0] - fmn[h * 3 + 0],
                        fmaxf(fmx[h * 3 + 1] - fmn[h * 3 + 1],
                              fmx[h * 3 + 2] - fmn[h * 3 + 2]));
            isc[h] = 1.0f / (0.55f * ext);   // (1+0.1)*0.5
        }
    }

    // ---- pre-transform to grid coords in registers; z-bucket histogram ----
    // vert hand h is sampled with bbox of hand (1-h); h==1 -> phi_right, h==0 -> phi_left
    int zb[2][VPT];
#pragma unroll
    for (int h = 0; h < 2; ++h) {
        const int hb = 1 - h;
        const float cx = cen[hb * 3 + 0], cy = cen[hb * 3 + 1], cz = cen[hb * 3 + 2];
        const float is = isc[hb];
#pragma unroll
        for (int k = 0; k < VPT; ++k) {
            int v = tid + k * NT;
            vx[h][k] = fmaf((vx[h][k] - cx) * is, 15.5f, 15.5f);
            vy[h][k] = fmaf((vy[h][k] - cy) * is, 15.5f, 15.5f);
            vz[h][k] = fmaf((vz[h][k] - cz) * is, 15.5f, 15.5f);
            int zbi = (int)fminf(fmaxf(floorf(vz[h][k]), 0.0f), 31.0f);
            zb[h][k] = zbi;
            if (v < NV) atomicAdd(&hist[zbi], 1);
        }
    }
    __syncthreads();

    // ---- exclusive prefix over 32 buckets (serial by t0 — trivial cost) ----
    if (tid == 0) {
        int run = 0;
#pragma unroll
        for (int i = 0; i < 32; ++i) { cursor[i] = run; run += hist[i]; }
    }
    __syncthreads();

    // ---- scatter into z-sorted LDS array ----
#pragma unroll
    for (int h = 0; h < 2; ++h) {
#pragma unroll
        for (int k = 0; k < VPT; ++k) {
            int v = tid + k * NT;
            if (v < NV) {
                int slot = atomicAdd(&cursor[zb[h][k]], 1);
                sorted[slot] = make_float4(vx[h][k], vy[h][k], vz[h][k],
                                           __int_as_float(h));
            }
        }
    }
    __syncthreads();

    // ---- gather in z-sorted order (L1-local windows) ----
    const float* volR = phi_right + (size_t)b * 32768;
    const float* volL = phi_left  + (size_t)b * 32768;

    float acc = 0.0f;
#pragma unroll
    for (int base = 0; base < NITEMS; base += NT) {
        int i = base + tid;
        if (i < NITEMS) {
            float4 it = sorted[i];
            const float* vol = __float_as_int(it.w) ? volR : volL;
            float ix = it.x, iy = it.y, iz = it.z;

            float x0f = fminf(fmaxf(floorf(ix), 0.0f), 31.0f);
            float y0f = fminf(fmaxf(floorf(iy), 0.0f), 31.0f);
            float z0f = fminf(fmaxf(floorf(iz), 0.0f), 31.0f);
            float fx = ix - x0f, fy = iy - y0f, fz = iz - z0f;  // unclamped (ref)
            int x0 = (int)x0f, y0 = (int)y0f, z0 = (int)z0f;
            int x1 = min(x0 + 1, 31), y1 = min(y0 + 1, 31), z1 = min(z0 + 1, 31);

            int o00 = z0 * 1024 + y0 * 32;
            int o01 = z0 * 1024 + y1 * 32;
            int o10 = z1 * 1024 + y0 * 32;
            int o11 = z1 * 1024 + y1 * 32;

            float a00 = vol[o00 + x0], b00 = vol[o00 + x1];
            float a01 = vol[o01 + x0], b01 = vol[o01 + x1];
            float a10 = vol[o10 + x0], b10 = vol[o10 + x1];
            float a11 = vol[o11 + x0], b11 = vol[o11 + x1];

            float c00 = a00 + fx * (b00 - a00);
            float c01 = a01 + fx * (b01 - a01);
            float c10 = a10 + fx * (b10 - a10);
            float c11 = a11 + fx * (b11 - a11);
            float c0  = c00 + fy * (c01 - c00);
            float c1  = c10 + fy * (c11 - c10);
            acc += c0 + fz * (c1 - c0);
        }
    }

    // ---- reduce & write ----
    acc *= 0.25f;   // / num_hand^2
#pragma unroll
    for (int off = 32; off > 0; off >>= 1) acc += __shfl_xor(acc, off, 64);
    if (lane == 0) rsum[wave] = acc;
    __syncthreads();
    if (tid == 0) out[b] = rsum[0] + rsum[1] + rsum[2] + rsum[3];
}

extern "C" void kernel_launch(void* const* d_in, const int* in_sizes, int n_in,
                              void* d_out, int out_size, void* d_ws, size_t ws_size,
                              hipStream_t stream) {
    const float* vertices  = (const float*)d_in[0];
    const float* phi_right = (const float*)d_in[1];
    const float* phi_left  = (const float*)d_in[2];
    float* out = (float*)d_out;

    newloss_sorted<<<dim3((unsigned)out_size), dim3(NT), 0, stream>>>(
        vertices, phi_right, phi_left, out);
}